// Round 8
// baseline (348.310 us; speedup 1.0000x reference)
//
#include <hip/hip_runtime.h>

#define B_N 8192
#define D_N 512
#define K_N 64
#define H_N 256
#define SC  4608   // K*K + D
#define R_T 16     // rows per block
#define NT  256    // 4 waves

typedef __attribute__((ext_vector_type(8))) short short8;
typedef __attribute__((ext_vector_type(4))) short short4v;
typedef __attribute__((ext_vector_type(4))) float f32x4;

__device__ __forceinline__ unsigned short f2bf(float f) {
  unsigned int u = __builtin_bit_cast(unsigned int, f);
  u += 0x7fff + ((u >> 16) & 1);      // RNE
  return (unsigned short)(u >> 16);
}
__device__ __forceinline__ float bf2f(unsigned short h) {
  unsigned int u = ((unsigned int)h) << 16;
  return __builtin_bit_cast(float, u);
}

// ---- workspace layout (bf16 elements), per layer ----
// W1T [256][512]  @ 0        (W1T[n][k] = W1[k][n])
// UT  [ 64][512]  @ 131072
// W2p [panelized] @ 163840   : idx = (((k*2+th)*16 + c)*64 + j)*8 + e
//                              value = W2[t][512+64k+j], t = th*128+(c>>2)*32+(c&3)*8+e
// W2bT[ 512][256] @ 1212416  (W2bT[n][t] = W2[t][n])
// VT  [ 512][ 64] @ 1343488
#define L_ELEMS 1376256

struct PrepParams {
  const float* W1[3]; const float* U[3]; const float* W2[3]; const float* V[3];
  short* ws;
};

__global__ __launch_bounds__(256) void prep_weights(PrepParams p) {
  const int y = blockIdx.y;           // 0..14
  const int l = y / 5, m = y - 5 * l;
  short* wsl = p.ws + (size_t)l * L_ELEMS;
  if (m == 2) {                       // W2p panelized
    const float* in = p.W2[l];
    short* out = wsl + 163840;
    const long total = 1048576;
    for (long e = (long)blockIdx.x * 256 + threadIdx.x; e < total;
         e += (long)gridDim.x * 256) {
      const int el = (int)(e & 7);
      const int j  = (int)((e >> 3) & 63);
      const int c  = (int)((e >> 9) & 15);
      const int th = (int)((e >> 13) & 1);
      const int k  = (int)(e >> 14);
      const int t  = th * 128 + (c >> 2) * 32 + (c & 3) * 8 + el;
      out[e] = (short)f2bf(in[(size_t)t * SC + 512 + 64 * k + j]);
    }
    return;
  }
  const float* in; short* out; int K, istride, ioff, kshift;
  switch (m) {
    case 0: in = p.W1[l]; out = wsl;           K = 512; istride = 256;  ioff = 0; kshift = 9; break;
    case 1: in = p.U[l];  out = wsl + 131072;  K = 512; istride = 64;   ioff = 0; kshift = 9; break;
    case 3: in = p.W2[l]; out = wsl + 1212416; K = 256; istride = 4608; ioff = 0; kshift = 8; break;
    default:in = p.V[l];  out = wsl + 1343488; K = 64;  istride = 512;  ioff = 0; kshift = 6; break;
  }
  const long total = (long)K * ((m == 0) ? 256 : (m == 1) ? 64 : (m == 3) ? 512 : 512);
  for (long e = (long)blockIdx.x * 256 + threadIdx.x; e < total;
       e += (long)gridDim.x * 256) {
    const int k = (int)(e & (K - 1));
    const int n = (int)(e >> kshift);
    out[e] = (short)f2bf(in[(size_t)k * istride + ioff + n]);
  }
}

struct Params {
  const float* x;
  const float* b1[3];
  const float* b2[3];
  const float* Wout;
  const float* bout;
  const short* ws;
  float* out;
};

#define XP 520   // xs pitch in shorts
#define HP 264
#define TP 72

// NT=256: each thread stages 4x16B per 16KB panel; dest wave-uniform + lane*16B
__device__ __forceinline__ void stage_panel(const short* W2p, short* dst,
                                            int s, int w, int lane) {
#pragma unroll
  for (int i = 0; i < 4; ++i) {
    const short* gp = W2p + ((size_t)s << 13) + (i << 11) + (w << 9) + (lane << 3);
    short* lp = dst + (i << 11) + (w << 9);
    __builtin_amdgcn_global_load_lds(
        (const __attribute__((address_space(1))) void*)gp,
        (__attribute__((address_space(3))) void*)lp, 16, 0, 0);
  }
}

__global__ __launch_bounds__(NT, 2) void apg_mfma(Params p) {
  __shared__ __attribute__((aligned(16))) short ring[2][8192]; // 32 KB panel dbuf
  __shared__ short xs[R_T][XP];     // 16.6 KB
  __shared__ short h1s[R_T][HP];    //  8.4 KB
  __shared__ short tmps[R_T][TP];   //  2.3 KB
  __shared__ float hs[R_T][68];     //  4.3 KB  -> total ~63 KB, 2 blocks/CU

  const int tid  = threadIdx.x;
  const int row0 = blockIdx.x * R_T;
  const int w    = tid >> 6;         // wave 0..3
  const int lane = tid & 63;
  const int l15  = tid & 15;
  const int g    = (tid & 63) >> 4;  // 0..3
  const int koff = g * 8;

  // ---- load x tile -> bf16 LDS ----
  {
    const float4* xg = (const float4*)(p.x + (size_t)row0 * D_N);
    for (int i = tid; i < R_T * D_N / 4; i += NT) {
      float4 v = xg[i];
      const int r = i >> 7;
      const int c = (i & 127) << 2;
      short4v s4 = { (short)f2bf(v.x), (short)f2bf(v.y), (short)f2bf(v.z), (short)f2bf(v.w) };
      *(short4v*)&xs[r][c] = s4;
    }
  }
  __syncthreads();

  for (int l = 0; l < 3; ++l) {
    const short* wsl  = p.ws + (size_t)l * L_ELEMS;
    const short* W1T  = wsl;
    const short* UT   = wsl + 131072;
    const short* W2p  = wsl + 163840;
    const short* W2bT = wsl + 1212416;
    const short* VT   = wsl + 1343488;
    const float* b1 = p.b1[l];
    const float* b2 = p.b2[l];

    // ---- A-operand x fragments, kept for stages A+B ----
    short8 aX[16];
#pragma unroll
    for (int kk = 0; kk < 16; ++kk)
      aX[kk] = *(const short8*)&xs[l15][kk * 32 + koff];

    // ---- stage A: h1 = relu(x @ W1 + b1); wave w -> n in [64w, 64w+64) ----
    for (int nf = 0; nf < 4; ++nf) {
      const int n0 = ((w << 2) + nf) << 4;
      const short* pb = W1T + ((size_t)(n0 + l15) << 9) + koff;
      short8 bf[16];
#pragma unroll
      for (int kk = 0; kk < 16; ++kk) bf[kk] = *(const short8*)(pb + kk * 32);
      f32x4 acc = {0.f, 0.f, 0.f, 0.f};
#pragma unroll
      for (int kk = 0; kk < 16; ++kk)
        acc = __builtin_amdgcn_mfma_f32_16x16x32_bf16(aX[kk], bf[kk], acc, 0, 0, 0);
      const float bb = b1[n0 + l15];
#pragma unroll
      for (int i = 0; i < 4; ++i)
        h1s[g * 4 + i][n0 + l15] = (short)f2bf(fmaxf(acc[i] + bb, 0.f));
    }

    // ---- stage B: h = x @ U (f32); wave w -> n-frag w ----
    {
      const int n0 = w << 4;
      const short* pb = UT + ((size_t)(n0 + l15) << 9) + koff;
      short8 bf[16];
#pragma unroll
      for (int kk = 0; kk < 16; ++kk) bf[kk] = *(const short8*)(pb + kk * 32);
      f32x4 acc = {0.f, 0.f, 0.f, 0.f};
#pragma unroll
      for (int kk = 0; kk < 16; ++kk)
        acc = __builtin_amdgcn_mfma_f32_16x16x32_bf16(aX[kk], bf[kk], acc, 0, 0, 0);
#pragma unroll
      for (int i = 0; i < 4; ++i) hs[g * 4 + i][n0 + l15] = acc[i];
    }
    __syncthreads();   // h1s, hs ready

    // ---- stage C: tmp[r][j] = sum_k h[r,k] * (h1@W2S + b2S)[r, 64k+j] ----
    // 128 16KB panels, 2-deep LDS ring via global_load_lds; __syncthreads
    // drains; the co-resident second block covers the drain stalls.
    {
      const int j0 = w << 4;
      short8 aH[8];
#pragma unroll
      for (int kk = 0; kk < 8; ++kk)
        aH[kk] = *(const short8*)&h1s[l15][kk * 32 + koff];

      // tacc init: einsum-bias term sum_k h[r,k]*b2[512+64k+j]
      float tacc[4] = {0.f, 0.f, 0.f, 0.f};
      {
        const float* pb2 = b2 + D_N + j0 + l15;
#pragma unroll 4
        for (int k = 0; k < K_N; ++k) {
          const float b2v = pb2[k << 6];
#pragma unroll
          for (int i = 0; i < 4; ++i)
            tacc[i] += hs[g * 4 + i][k] * b2v;
        }
      }

      const int pbo = (j0 + l15) << 3;
      stage_panel(W2p, &ring[0][0], 0, w, lane);
      __syncthreads();               // panel 0 staged

#pragma unroll 1
      for (int k = 0; k < K_N; ++k) {
        // even phase: panel 2k in slot0; prefetch 2k+1 -> slot1
        stage_panel(W2p, &ring[1][0], 2 * k + 1, w, lane);
        const short* pb0 = &ring[0][0] + pbo;
        f32x4 sacc = {0.f, 0.f, 0.f, 0.f};
#pragma unroll
        for (int kkl = 0; kkl < 4; ++kkl) {
          short8 bfrag = *(const short8*)(pb0 + ((kkl * 4 + g) << 9));
          sacc = __builtin_amdgcn_mfma_f32_16x16x32_bf16(aH[kkl], bfrag, sacc, 0, 0, 0);
        }
        __syncthreads();             // slot1 staged; slot0 reads done
        // odd phase: panel 2k+1 in slot1; prefetch 2k+2 -> slot0
        if (k + 1 < K_N) stage_panel(W2p, &ring[0][0], 2 * k + 2, w, lane);
        const short* pb1 = &ring[1][0] + pbo;
#pragma unroll
        for (int kkl = 0; kkl < 4; ++kkl) {
          short8 bfrag = *(const short8*)(pb1 + ((kkl * 4 + g) << 9));
          sacc = __builtin_amdgcn_mfma_f32_16x16x32_bf16(aH[4 + kkl], bfrag, sacc, 0, 0, 0);
        }
#pragma unroll
        for (int i = 0; i < 4; ++i)
          tacc[i] += hs[g * 4 + i][k] * sacc[i];
        __syncthreads();             // slot0 staged; slot1 reads done
      }
#pragma unroll
      for (int i = 0; i < 4; ++i)
        tmps[g * 4 + i][j0 + l15] = (short)f2bf(tacc[i]);
    }
    __syncthreads();

    // ---- stage D: xnew = relu(tmp@V + h1@W2[:, :512] + b2[:512]) -> xs ----
    {
      short8 aT[2], aD[8];
#pragma unroll
      for (int kk = 0; kk < 2; ++kk)
        aT[kk] = *(const short8*)&tmps[l15][kk * 32 + koff];
#pragma unroll
      for (int kk = 0; kk < 8; ++kk)
        aD[kk] = *(const short8*)&h1s[l15][kk * 32 + koff];
      for (int ti = 0; ti < 8; ++ti) {
        const int n0 = ((ti << 2) + w) << 4;   // 4 waves interleave 32 n-frags
        const short* pv = VT + ((size_t)(n0 + l15) << 6) + koff;
        const short* pw = W2bT + ((size_t)(n0 + l15) << 8) + koff;
        short8 bv[2], bw[8];
#pragma unroll
        for (int kk = 0; kk < 2; ++kk) bv[kk] = *(const short8*)(pv + kk * 32);
#pragma unroll
        for (int kk = 0; kk < 8; ++kk) bw[kk] = *(const short8*)(pw + kk * 32);
        f32x4 acc = {0.f, 0.f, 0.f, 0.f};
#pragma unroll
        for (int kk = 0; kk < 2; ++kk)
          acc = __builtin_amdgcn_mfma_f32_16x16x32_bf16(aT[kk], bv[kk], acc, 0, 0, 0);
#pragma unroll
        for (int kk = 0; kk < 8; ++kk)
          acc = __builtin_amdgcn_mfma_f32_16x16x32_bf16(aD[kk], bw[kk], acc, 0, 0, 0);
        const float bb = b2[n0 + l15];
#pragma unroll
        for (int i = 0; i < 4; ++i)
          xs[g * 4 + i][n0 + l15] = (short)f2bf(fmaxf(acc[i] + bb, 0.f));
      }
    }
    __syncthreads();
  }

  // ---- out = x @ Wout + bout ----
  {
    const int r  = tid >> 4;
    const int cl = tid & 15;
    float acc = 0.f;
    for (int c = cl; c < D_N; c += 16)
      acc = fmaf(bf2f((unsigned short)xs[r][c]), p.Wout[c], acc);
#pragma unroll
    for (int s = 1; s < 16; s <<= 1) acc += __shfl_xor(acc, s, 64);
    if (cl == 0) p.out[row0 + r] = acc + p.bout[0];
  }
}

extern "C" void kernel_launch(void* const* d_in, const int* in_sizes, int n_in,
                              void* d_out, int out_size, void* d_ws, size_t ws_size,
                              hipStream_t stream) {
  (void)in_sizes; (void)n_in; (void)ws_size; (void)out_size;
  PrepParams pp;
  Params p;
  p.x = (const float*)d_in[0];
  for (int l = 0; l < 3; ++l) {
    const int base = 1 + l * 6;
    pp.U[l]  = (const float*)d_in[base + 0];
    pp.V[l]  = (const float*)d_in[base + 1];
    pp.W1[l] = (const float*)d_in[base + 2];
    p.b1[l]  = (const float*)d_in[base + 3];
    pp.W2[l] = (const float*)d_in[base + 4];
    p.b2[l]  = (const float*)d_in[base + 5];
  }
  p.Wout = (const float*)d_in[19];
  p.bout = (const float*)d_in[20];
  p.ws   = (const short*)d_ws;
  p.out  = (float*)d_out;
  pp.ws  = (short*)d_ws;

  hipLaunchKernelGGL(prep_weights, dim3(1024, 15), dim3(256), 0, stream, pp);
  hipLaunchKernelGGL(apg_mfma, dim3(B_N / R_T), dim3(NT), 0, stream, p);
}

// Round 9
// 331.748 us; speedup vs baseline: 1.0499x; 1.0499x over previous
//
#include <hip/hip_runtime.h>

#define B_N 8192
#define D_N 512
#define K_N 64
#define H_N 256
#define SC  4608   // K*K + D
#define R_T 32     // rows per block
#define NT  512    // 8 waves

typedef __attribute__((ext_vector_type(8))) short short8;
typedef __attribute__((ext_vector_type(4))) short short4v;
typedef __attribute__((ext_vector_type(4))) float f32x4;

__device__ __forceinline__ unsigned short f2bf(float f) {
  unsigned int u = __builtin_bit_cast(unsigned int, f);
  u += 0x7fff + ((u >> 16) & 1);      // RNE
  return (unsigned short)(u >> 16);
}
__device__ __forceinline__ float bf2f(unsigned short h) {
  unsigned int u = ((unsigned int)h) << 16;
  return __builtin_bit_cast(float, u);
}

// ---- workspace layout (bf16 elements), per layer ----
// W1T [256][512]  @ 0        (W1T[n][k] = W1[k][n])
// UT  [ 64][512]  @ 131072
// W2P [64 panels] @ 163840   : panel kg (16384 elems, 32KB) holds W2S cols
//                  [64k..64k+64) x t[0..256), XOR-swizzled:
//                  elem = kg*16384 + ((nl*256 + t) ^ ((nl&7)<<3)),
//                  value = W2[t][512 + 64*kg + nl]
// W2bT[ 512][256] @ 1212416  (W2bT[n][t] = W2[t][n])
// VT  [ 512][ 64] @ 1343488
#define L_ELEMS 1376256

struct PrepParams {
  const float* W1[3]; const float* U[3]; const float* W2[3]; const float* V[3];
  short* ws;
};

__global__ __launch_bounds__(256) void prep_weights(PrepParams p) {
  const int y = blockIdx.y;           // 0..14
  const int l = y / 5, m = y - 5 * l;
  short* wsl = p.ws + (size_t)l * L_ELEMS;
  if (m == 2) {                       // W2P panel-contiguous + XOR swizzle
    const float* in = p.W2[l];
    short* out = wsl + 163840;
    const long total = 1048576;
    for (long e = (long)blockIdx.x * 256 + threadIdx.x; e < total;
         e += (long)gridDim.x * 256) {
      const int kg = (int)(e >> 14);
      const int q  = (int)(e & 16383);
      const int nl = q >> 8;
      const int t  = (q & 255) ^ ((nl & 7) << 3);
      out[e] = (short)f2bf(in[(size_t)t * SC + 512 + 64 * kg + nl]);
    }
    return;
  }
  const float* in; short* out; int K, istride, ioff, kshift;
  switch (m) {
    case 0: in = p.W1[l]; out = wsl;           K = 512; istride = 256;  ioff = 0; kshift = 9; break;
    case 1: in = p.U[l];  out = wsl + 131072;  K = 512; istride = 64;   ioff = 0; kshift = 9; break;
    case 3: in = p.W2[l]; out = wsl + 1212416; K = 256; istride = 4608; ioff = 0; kshift = 8; break;
    default:in = p.V[l];  out = wsl + 1343488; K = 64;  istride = 512;  ioff = 0; kshift = 6; break;
  }
  const long total = (long)K * ((m == 0) ? 256 : (m == 1) ? 64 : 512);
  for (long e = (long)blockIdx.x * 256 + threadIdx.x; e < total;
       e += (long)gridDim.x * 256) {
    const int k = (int)(e & (K - 1));
    const int n = (int)(e >> kshift);
    out[e] = (short)f2bf(in[(size_t)k * istride + ioff + n]);
  }
}

struct Params {
  const float* x;
  const float* b1[3];
  const float* b2[3];
  const float* Wout;
  const float* bout;
  const short* ws;
  float* out;
};

// stage one 32KB W2P panel (16384 shorts): 512 threads x 4 x 16B, linear dest
__device__ __forceinline__ void stage_panel(const short* W2p, short* dst,
                                            int s, int w, int lane) {
#pragma unroll
  for (int i = 0; i < 4; ++i) {
    const short* gp = W2p + ((size_t)s << 14) + (i << 12) + (w << 9) + (lane << 3);
    short* lp = dst + (i << 12) + (w << 9);   // wave-uniform; HW adds lane*16B
    __builtin_amdgcn_global_load_lds(
        (const __attribute__((address_space(1))) void*)gp,
        (__attribute__((address_space(3))) void*)lp, 16, 0, 0);
  }
}

__global__ __launch_bounds__(NT, 2) void apg_mfma(Params p) {
  __shared__ __attribute__((aligned(16))) short ringf[3 * 16384]; // 96 KB panel ring
  __shared__ __attribute__((aligned(16))) short xsf[R_T * D_N];   // 32 KB x, swizzled
  __shared__ __attribute__((aligned(16))) short h1f[R_T * H_N];   // 16 KB h1, swizzled
  __shared__ __attribute__((aligned(16))) short tmf[R_T * K_N];   //  4 KB tmp, swizzled
  __shared__ float hs[R_T][K_N];                                  //  8 KB h (f32)

  const int tid  = threadIdx.x;
  const int row0 = blockIdx.x * R_T;
  const int w    = tid >> 6;         // wave 0..7
  const int lane = tid & 63;
  const int l15  = tid & 15;
  const int g    = (tid & 63) >> 4;  // 0..3
  const int koff = g * 8;
  const int mh   = w >> 2;           // row-half 0/1 (16 rows)
  const int nq   = w & 3;            // col-quarter
  const int sw15 = (l15 & 7) << 3;   // per-lane XOR (elems) for A-frag rows

  // ---- load x tile (f32 global -> bf16 swizzled LDS) ----
  {
    const float4* xg = (const float4*)(p.x + (size_t)row0 * D_N);
    for (int i = tid; i < R_T * D_N / 4; i += NT) {
      float4 v = xg[i];
      const int r = i >> 7;
      const int c = (i & 127) << 2;
      short4v s4 = { (short)f2bf(v.x), (short)f2bf(v.y), (short)f2bf(v.z), (short)f2bf(v.w) };
      *(short4v*)&xsf[(r * D_N + c) ^ ((r & 7) << 3)] = s4;
    }
  }
  __syncthreads();

  for (int l = 0; l < 3; ++l) {
    const short* wsl  = p.ws + (size_t)l * L_ELEMS;
    const short* W1T  = wsl;
    const short* UT   = wsl + 131072;
    const short* W2p  = wsl + 163840;
    const short* W2bT = wsl + 1212416;
    const short* VT   = wsl + 1343488;
    const float* b1 = p.b1[l];
    const float* b2 = p.b2[l];

    // ---- A-operand x fragments for this wave's 16 rows ----
    short8 aX[16];
#pragma unroll
    for (int kk = 0; kk < 16; ++kk)
      aX[kk] = *(const short8*)&xsf[((mh * 16 + l15) * D_N + kk * 32 + koff) ^ sw15];

    // ---- h1 = relu(x@W1+b1): wave -> rows [16mh,16mh+16), cols [64nq,64nq+64) ----
    for (int nf = 0; nf < 4; ++nf) {
      const int n0 = nq * 64 + nf * 16;
      const short* pb = W1T + ((size_t)(n0 + l15) << 9) + koff;
      short8 bf[16];
#pragma unroll
      for (int kk = 0; kk < 16; ++kk) bf[kk] = *(const short8*)(pb + kk * 32);
      f32x4 acc = {0.f, 0.f, 0.f, 0.f};
#pragma unroll
      for (int kk = 0; kk < 16; ++kk)
        acc = __builtin_amdgcn_mfma_f32_16x16x32_bf16(aX[kk], bf[kk], acc, 0, 0, 0);
      const float bb = b1[n0 + l15];
#pragma unroll
      for (int i = 0; i < 4; ++i) {
        const int r = mh * 16 + g * 4 + i;
        h1f[(r * H_N + n0 + l15) ^ (((g * 4 + i) & 7) << 3)] =
            (short)f2bf(fmaxf(acc[i] + bb, 0.f));
      }
    }

    // ---- h = x@U (f32): wave -> rows [16mh..), cols [16nq..) ----
    {
      const int n0 = nq << 4;
      const short* pb = UT + ((size_t)(n0 + l15) << 9) + koff;
      short8 bf[16];
#pragma unroll
      for (int kk = 0; kk < 16; ++kk) bf[kk] = *(const short8*)(pb + kk * 32);
      f32x4 acc = {0.f, 0.f, 0.f, 0.f};
#pragma unroll
      for (int kk = 0; kk < 16; ++kk)
        acc = __builtin_amdgcn_mfma_f32_16x16x32_bf16(aX[kk], bf[kk], acc, 0, 0, 0);
#pragma unroll
      for (int i = 0; i < 4; ++i) hs[mh * 16 + g * 4 + i][n0 + l15] = acc[i];
    }
    __syncthreads();   // h1f, hs ready

    // ---- stage C: 64 panels (32KB) through 3-deep ring, counted vmcnt ----
    {
      short8 aH[8];
#pragma unroll
      for (int kk = 0; kk < 8; ++kk)
        aH[kk] = *(const short8*)&h1f[((mh * 16 + l15) * H_N + kk * 32 + koff) ^ sw15];

      // tacc init: sum_k h[r,k]*b2[512+64k+j]  (outside counted region)
      float tacc[4] = {0.f, 0.f, 0.f, 0.f};
      {
        const float* pb2 = b2 + D_N + nq * 16 + l15;
#pragma unroll 4
        for (int k = 0; k < K_N; ++k) {
          const float b2v = pb2[k << 6];
#pragma unroll
          for (int i = 0; i < 4; ++i)
            tacc[i] += hs[mh * 16 + g * 4 + i][k] * b2v;
        }
      }

      asm volatile("s_waitcnt vmcnt(0)" ::: "memory");
      stage_panel(W2p, ringf,         0, w, lane);
      stage_panel(W2p, ringf + 16384, 1, w, lane);

      const int nl = nq * 16 + l15;
      int rd = 0, wr = 2;
#pragma unroll 1
      for (int s = 0; s < 64; ++s) {
        if (s < 63) asm volatile("s_waitcnt vmcnt(4)" ::: "memory");
        else        asm volatile("s_waitcnt vmcnt(0)" ::: "memory");
        __builtin_amdgcn_s_barrier();
        if (s < 62) {
          stage_panel(W2p, ringf + wr * 16384, s + 2, w, lane);
          wr = (wr == 2) ? 0 : wr + 1;
        }
        const short* pb = ringf + rd * 16384;
        rd = (rd == 2) ? 0 : rd + 1;
        short8 bf8[8];
#pragma unroll
        for (int kk = 0; kk < 8; ++kk)
          bf8[kk] = *(const short8*)&pb[((nl << 8) + kk * 32 + koff) ^ ((nl & 7) << 3)];
        f32x4 sacc = {0.f, 0.f, 0.f, 0.f};
#pragma unroll
        for (int kk = 0; kk < 8; ++kk)
          sacc = __builtin_amdgcn_mfma_f32_16x16x32_bf16(aH[kk], bf8[kk], sacc, 0, 0, 0);
#pragma unroll
        for (int i = 0; i < 4; ++i)
          tacc[i] += hs[mh * 16 + g * 4 + i][s] * sacc[i];
      }

#pragma unroll
      for (int i = 0; i < 4; ++i) {
        const int r = mh * 16 + g * 4 + i;
        tmf[(r * K_N + nq * 16 + l15) ^ (((g * 4 + i) & 7) << 3)] = (short)f2bf(tacc[i]);
      }
      __syncthreads();

      // ---- stage D: xnew = relu(tmp@V + h1@W2b + b2[:512]) -> xsf ----
      short8 aT[2];
#pragma unroll
      for (int kk = 0; kk < 2; ++kk)
        aT[kk] = *(const short8*)&tmf[((mh * 16 + l15) * K_N + kk * 32 + koff) ^ sw15];
      for (int ti = 0; ti < 8; ++ti) {
        const int n0 = ((ti << 2) + nq) << 4;
        const short* pv = VT + ((size_t)(n0 + l15) << 6) + koff;
        const short* pw = W2bT + ((size_t)(n0 + l15) << 8) + koff;
        short8 bv[2], bw[8];
#pragma unroll
        for (int kk = 0; kk < 2; ++kk) bv[kk] = *(const short8*)(pv + kk * 32);
#pragma unroll
        for (int kk = 0; kk < 8; ++kk) bw[kk] = *(const short8*)(pw + kk * 32);
        f32x4 acc = {0.f, 0.f, 0.f, 0.f};
#pragma unroll
        for (int kk = 0; kk < 2; ++kk)
          acc = __builtin_amdgcn_mfma_f32_16x16x32_bf16(aT[kk], bv[kk], acc, 0, 0, 0);
#pragma unroll
        for (int kk = 0; kk < 8; ++kk)
          acc = __builtin_amdgcn_mfma_f32_16x16x32_bf16(aH[kk], bw[kk], acc, 0, 0, 0);
        const float bb = b2[n0 + l15];
#pragma unroll
        for (int i = 0; i < 4; ++i) {
          const int r = mh * 16 + g * 4 + i;
          xsf[(r * D_N + n0 + l15) ^ (((g * 4 + i) & 7) << 3)] =
              (short)f2bf(fmaxf(acc[i] + bb, 0.f));
        }
      }
    }
    __syncthreads();
  }

  // ---- out = x @ Wout + bout (32 rows, 16 lanes each) ----
  {
    const int r  = tid >> 4;
    const int cl = tid & 15;
    float acc = 0.f;
    for (int c = cl; c < D_N; c += 16)
      acc = fmaf(bf2f((unsigned short)xsf[(r * D_N + c) ^ ((r & 7) << 3)]),
                 p.Wout[c], acc);
#pragma unroll
    for (int s = 1; s < 16; s <<= 1) acc += __shfl_xor(acc, s, 64);
    if (cl == 0) p.out[row0 + r] = acc + p.bout[0];
  }
}

extern "C" void kernel_launch(void* const* d_in, const int* in_sizes, int n_in,
                              void* d_out, int out_size, void* d_ws, size_t ws_size,
                              hipStream_t stream) {
  (void)in_sizes; (void)n_in; (void)ws_size; (void)out_size;
  PrepParams pp;
  Params p;
  p.x = (const float*)d_in[0];
  for (int l = 0; l < 3; ++l) {
    const int base = 1 + l * 6;
    pp.U[l]  = (const float*)d_in[base + 0];
    pp.V[l]  = (const float*)d_in[base + 1];
    pp.W1[l] = (const float*)d_in[base + 2];
    p.b1[l]  = (const float*)d_in[base + 3];
    pp.W2[l] = (const float*)d_in[base + 4];
    p.b2[l]  = (const float*)d_in[base + 5];
  }
  p.Wout = (const float*)d_in[19];
  p.bout = (const float*)d_in[20];
  p.ws   = (const short*)d_ws;
  p.out  = (float*)d_out;
  pp.ws  = (short*)d_ws;

  hipLaunchKernelGGL(prep_weights, dim3(1024, 15), dim3(256), 0, stream, pp);
  hipLaunchKernelGGL(apg_mfma, dim3(B_N / R_T), dim3(NT), 0, stream, p);
}

// Round 10
// 259.036 us; speedup vs baseline: 1.3446x; 1.2807x over previous
//
#include <hip/hip_runtime.h>

#define B_N 8192
#define D_N 512
#define K_N 64
#define H_N 256
#define SC  4608   // K*K + D
#define R_T 32     // rows per block
#define NT  512    // 8 waves

typedef __attribute__((ext_vector_type(8))) short short8;
typedef __attribute__((ext_vector_type(4))) short short4v;
typedef __attribute__((ext_vector_type(4))) float f32x4;

__device__ __forceinline__ unsigned short f2bf(float f) {
  unsigned int u = __builtin_bit_cast(unsigned int, f);
  u += 0x7fff + ((u >> 16) & 1);      // RNE
  return (unsigned short)(u >> 16);
}
__device__ __forceinline__ float bf2f(unsigned short h) {
  unsigned int u = ((unsigned int)h) << 16;
  return __builtin_bit_cast(float, u);
}

// ---- workspace layout (bf16 elements), per layer ----
// W1T [256][512]  @ 0        (W1T[n][k] = W1[k][n])
// UT  [ 64][512]  @ 131072
// W2P [64 panels] @ 163840   : panel kg (16384 elems = 32KB), j-inner layout:
//                  idx = kg*16384 + (tc*64 + j)*8 + te
//                  value = W2[t][512 + 64*kg + j], t = tc*8 + te
//                  (B-frag for (kk,g): 16B at ((4kk+g)*64 + j)*8 -> lane-contig)
// W2bT[ 512][256] @ 1212416  (W2bT[n][t] = W2[t][n])
// VT  [ 512][ 64] @ 1343488
#define L_ELEMS 1376256

struct PrepParams {
  const float* W1[3]; const float* U[3]; const float* W2[3]; const float* V[3];
  short* ws;
};

__global__ __launch_bounds__(256) void prep_weights(PrepParams p) {
  const int y = blockIdx.y;           // 0..14
  const int l = y / 5, m = y - 5 * l;
  short* wsl = p.ws + (size_t)l * L_ELEMS;
  if (m == 2) {                       // W2P j-inner panels
    const float* in = p.W2[l];
    short* out = wsl + 163840;
    const long total = 1048576;
    for (long e = (long)blockIdx.x * 256 + threadIdx.x; e < total;
         e += (long)gridDim.x * 256) {
      const int te = (int)(e & 7);
      const int j  = (int)((e >> 3) & 63);
      const int tc = (int)((e >> 9) & 31);
      const int kg = (int)(e >> 14);
      const int t  = tc * 8 + te;
      out[e] = (short)f2bf(in[(size_t)t * SC + 512 + 64 * kg + j]);
    }
    return;
  }
  const float* in; short* out; int K, istride, ioff, kshift;
  switch (m) {
    case 0: in = p.W1[l]; out = wsl;           K = 512; istride = 256;  ioff = 0; kshift = 9; break;
    case 1: in = p.U[l];  out = wsl + 131072;  K = 512; istride = 64;   ioff = 0; kshift = 9; break;
    case 3: in = p.W2[l]; out = wsl + 1212416; K = 256; istride = 4608; ioff = 0; kshift = 8; break;
    default:in = p.V[l];  out = wsl + 1343488; K = 64;  istride = 512;  ioff = 0; kshift = 6; break;
  }
  const long total = (long)K * ((m == 0) ? 256 : (m == 1) ? 64 : 512);
  for (long e = (long)blockIdx.x * 256 + threadIdx.x; e < total;
       e += (long)gridDim.x * 256) {
    const int k = (int)(e & (K - 1));
    const int n = (int)(e >> kshift);
    out[e] = (short)f2bf(in[(size_t)k * istride + ioff + n]);
  }
}

struct Params {
  const float* x;
  const float* b1[3];
  const float* b2[3];
  const float* Wout;
  const float* bout;
  const short* ws;
  float* out;
};

#define XP 520   // xs pitch in shorts
#define HP 264
#define TP 72

// stage one 32KB panel (16384 shorts): 512 threads x 4 x 16B, linear dest
__device__ __forceinline__ void stage_panel32(const short* W2p, short* dst,
                                              int kg, int w, int lane) {
#pragma unroll
  for (int i = 0; i < 4; ++i) {
    const short* gp = W2p + ((size_t)kg << 14) + (i << 12) + (w << 9) + (lane << 3);
    short* lp = dst + (i << 12) + (w << 9);   // wave-uniform; HW adds lane*16B
    __builtin_amdgcn_global_load_lds(
        (const __attribute__((address_space(1))) void*)gp,
        (__attribute__((address_space(3))) void*)lp, 16, 0, 0);
  }
}

__global__ __launch_bounds__(NT, 1) void apg_mfma(Params p) {
  __shared__ __attribute__((aligned(16))) short ring[4][16384]; // 128 KB panel ring
  __shared__ short h1s[R_T][HP];    // 16.9 KB
  __shared__ short tmps[R_T][TP];   //  4.6 KB
  __shared__ float hs[R_T][68];     //  8.7 KB  (pad 68: conflict-free)
  // x tile aliases ring[0..] (33.3 KB): consumed into regs in A/B before C
  // clobbers the ring; rewritten by D after C fully drains.
  short (*xs)[XP] = (short (*)[XP]) & ring[0][0];

  const int tid  = threadIdx.x;
  const int row0 = blockIdx.x * R_T;
  const int w    = tid >> 6;         // wave 0..7
  const int lane = tid & 63;
  const int l15  = tid & 15;
  const int g    = (tid & 63) >> 4;  // 0..3
  const int koff = g * 8;
  const int rh   = w >> 2;           // row-half 0/1
  const int nq   = w & 3;            // col-quarter
  const int rbase = rh * 16;

  // ---- load x tile -> bf16 LDS ----
  {
    const float4* xg = (const float4*)(p.x + (size_t)row0 * D_N);
    for (int i = tid; i < R_T * D_N / 4; i += NT) {
      float4 v = xg[i];
      const int r = i >> 7;
      const int c = (i & 127) << 2;
      short4v s4 = { (short)f2bf(v.x), (short)f2bf(v.y), (short)f2bf(v.z), (short)f2bf(v.w) };
      *(short4v*)&xs[r][c] = s4;
    }
  }
  __syncthreads();

  for (int l = 0; l < 3; ++l) {
    const short* wsl  = p.ws + (size_t)l * L_ELEMS;
    const short* W1T  = wsl;
    const short* UT   = wsl + 131072;
    const short* W2p  = wsl + 163840;
    const short* W2bT = wsl + 1212416;
    const short* VT   = wsl + 1343488;
    const float* b1 = p.b1[l];
    const float* b2 = p.b2[l];

    // ---- A-operand x fragments (rows rbase..rbase+16), kept for stages A+B ----
    short8 aX[16];
#pragma unroll
    for (int kk = 0; kk < 16; ++kk)
      aX[kk] = *(const short8*)&xs[rbase + l15][kk * 32 + koff];

    // ---- stage A: h1 = relu(x @ W1 + b1); wave -> 4 n-frags of its row-half ----
    for (int nf = 0; nf < 4; ++nf) {
      const int n0 = ((nq << 2) + nf) << 4;
      const short* pb = W1T + ((size_t)(n0 + l15) << 9) + koff;
      short8 bf[16];
#pragma unroll
      for (int kk = 0; kk < 16; ++kk) bf[kk] = *(const short8*)(pb + kk * 32);
      f32x4 acc = {0.f, 0.f, 0.f, 0.f};
#pragma unroll
      for (int kk = 0; kk < 16; ++kk)
        acc = __builtin_amdgcn_mfma_f32_16x16x32_bf16(aX[kk], bf[kk], acc, 0, 0, 0);
      const float bb = b1[n0 + l15];
#pragma unroll
      for (int i = 0; i < 4; ++i)
        h1s[rbase + g * 4 + i][n0 + l15] = (short)f2bf(fmaxf(acc[i] + bb, 0.f));
    }

    // ---- stage B: h = x @ U (f32); wave -> n-frag nq, its row-half ----
    {
      const int n0 = nq << 4;
      const short* pb = UT + ((size_t)(n0 + l15) << 9) + koff;
      short8 bf[16];
#pragma unroll
      for (int kk = 0; kk < 16; ++kk) bf[kk] = *(const short8*)(pb + kk * 32);
      f32x4 acc = {0.f, 0.f, 0.f, 0.f};
#pragma unroll
      for (int kk = 0; kk < 16; ++kk)
        acc = __builtin_amdgcn_mfma_f32_16x16x32_bf16(aX[kk], bf[kk], acc, 0, 0, 0);
#pragma unroll
      for (int i = 0; i < 4; ++i) hs[rbase + g * 4 + i][n0 + l15] = acc[i];
    }
    __syncthreads();   // h1s, hs ready; xs regs consumed -> ring free

    // ---- stage C: tmp[r][j] = sum_k h[r,k] * (h1@W2S + b2S)[r, 64k+j] ----
    // 64 32KB kg-panels, 4-deep ring, stage 3 ahead (96KB in flight),
    // counted vmcnt(8); block-dephased start kg.
    {
      const int kg0 = blockIdx.x & 63;
      short8 aH[8];
#pragma unroll
      for (int kk = 0; kk < 8; ++kk)
        aH[kk] = *(const short8*)&h1s[rbase + l15][kk * 32 + koff];

      // tacc init: sum_k h[r,k]*b2[512+64k+j]  (outside counted region)
      float tacc[4] = {0.f, 0.f, 0.f, 0.f};
      {
        const float* pb2 = b2 + D_N + nq * 16 + l15;
#pragma unroll 4
        for (int k = 0; k < K_N; ++k) {
          const float b2v = pb2[k << 6];
#pragma unroll
          for (int i = 0; i < 4; ++i)
            tacc[i] += hs[rbase + g * 4 + i][k] * b2v;
        }
      }

      asm volatile("s_waitcnt vmcnt(0)" ::: "memory");
      stage_panel32(W2p, &ring[0][0], kg0, w, lane);
      stage_panel32(W2p, &ring[1][0], (kg0 + 1) & 63, w, lane);
      stage_panel32(W2p, &ring[2][0], (kg0 + 2) & 63, w, lane);

      const int nl = nq * 16 + l15;
#pragma unroll 1
      for (int s = 0; s < 64; ++s) {
        if (s < 62)      asm volatile("s_waitcnt vmcnt(8)" ::: "memory");
        else if (s == 62) asm volatile("s_waitcnt vmcnt(4)" ::: "memory");
        else             asm volatile("s_waitcnt vmcnt(0)" ::: "memory");
        __builtin_amdgcn_s_barrier();
        if (s < 61)
          stage_panel32(W2p, &ring[(s + 3) & 3][0], (kg0 + s + 3) & 63, w, lane);

        const short* pb = &ring[s & 3][0] + (nl << 3);
        short8 bf8[8];
#pragma unroll
        for (int kk = 0; kk < 8; ++kk)
          bf8[kk] = *(const short8*)(pb + ((4 * kk + g) << 9));
        f32x4 sacc = {0.f, 0.f, 0.f, 0.f};
#pragma unroll
        for (int kk = 0; kk < 8; ++kk)
          sacc = __builtin_amdgcn_mfma_f32_16x16x32_bf16(aH[kk], bf8[kk], sacc, 0, 0, 0);
        const int kga = (kg0 + s) & 63;
#pragma unroll
        for (int i = 0; i < 4; ++i)
          tacc[i] += hs[rbase + g * 4 + i][kga] * sacc[i];
      }

#pragma unroll
      for (int i = 0; i < 4; ++i)
        tmps[rbase + g * 4 + i][nq * 16 + l15] = (short)f2bf(tacc[i]);
    }
    __syncthreads();

    // ---- stage D: xnew = relu(tmp@V + h1@W2b + b2[:512]) -> xs (ring area) ----
    {
      short8 aT[2], aD[8];
#pragma unroll
      for (int kk = 0; kk < 2; ++kk)
        aT[kk] = *(const short8*)&tmps[rbase + l15][kk * 32 + koff];
#pragma unroll
      for (int kk = 0; kk < 8; ++kk)
        aD[kk] = *(const short8*)&h1s[rbase + l15][kk * 32 + koff];
      for (int ti = 0; ti < 8; ++ti) {
        const int n0 = ((ti << 2) + nq) << 4;
        const short* pv = VT + ((size_t)(n0 + l15) << 6) + koff;
        const short* pw = W2bT + ((size_t)(n0 + l15) << 8) + koff;
        short8 bv[2], bw[8];
#pragma unroll
        for (int kk = 0; kk < 2; ++kk) bv[kk] = *(const short8*)(pv + kk * 32);
#pragma unroll
        for (int kk = 0; kk < 8; ++kk) bw[kk] = *(const short8*)(pw + kk * 32);
        f32x4 acc = {0.f, 0.f, 0.f, 0.f};
#pragma unroll
        for (int kk = 0; kk < 2; ++kk)
          acc = __builtin_amdgcn_mfma_f32_16x16x32_bf16(aT[kk], bv[kk], acc, 0, 0, 0);
#pragma unroll
        for (int kk = 0; kk < 8; ++kk)
          acc = __builtin_amdgcn_mfma_f32_16x16x32_bf16(aD[kk], bw[kk], acc, 0, 0, 0);
        const float bb = b2[n0 + l15];
#pragma unroll
        for (int i = 0; i < 4; ++i)
          xs[rbase + g * 4 + i][n0 + l15] = (short)f2bf(fmaxf(acc[i] + bb, 0.f));
      }
    }
    __syncthreads();
  }

  // ---- out = x @ Wout + bout ----
  {
    const int r  = tid >> 4;
    const int cl = tid & 15;
    float acc = 0.f;
    for (int c = cl; c < D_N; c += 16)
      acc = fmaf(bf2f((unsigned short)xs[r][c]), p.Wout[c], acc);
#pragma unroll
    for (int s = 1; s < 16; s <<= 1) acc += __shfl_xor(acc, s, 64);
    if (cl == 0) p.out[row0 + r] = acc + p.bout[0];
  }
}

extern "C" void kernel_launch(void* const* d_in, const int* in_sizes, int n_in,
                              void* d_out, int out_size, void* d_ws, size_t ws_size,
                              hipStream_t stream) {
  (void)in_sizes; (void)n_in; (void)ws_size; (void)out_size;
  PrepParams pp;
  Params p;
  p.x = (const float*)d_in[0];
  for (int l = 0; l < 3; ++l) {
    const int base = 1 + l * 6;
    pp.U[l]  = (const float*)d_in[base + 0];
    pp.V[l]  = (const float*)d_in[base + 1];
    pp.W1[l] = (const float*)d_in[base + 2];
    p.b1[l]  = (const float*)d_in[base + 3];
    pp.W2[l] = (const float*)d_in[base + 4];
    p.b2[l]  = (const float*)d_in[base + 5];
  }
  p.Wout = (const float*)d_in[19];
  p.bout = (const float*)d_in[20];
  p.ws   = (const short*)d_ws;
  p.out  = (float*)d_out;
  pp.ws  = (short*)d_ws;

  hipLaunchKernelGGL(prep_weights, dim3(1024, 15), dim3(256), 0, stream, pp);
  hipLaunchKernelGGL(apg_mfma, dim3(B_N / R_T), dim3(NT), 0, stream, p);
}

// Round 11
// 222.661 us; speedup vs baseline: 1.5643x; 1.1634x over previous
//
#include <hip/hip_runtime.h>

#define B_N 8192
#define D_N 512
#define K_N 64
#define H_N 256
#define SC  4608   // K*K + D
#define R_T 32     // rows per block
#define NT  512    // 8 waves

typedef __attribute__((ext_vector_type(8))) short short8;
typedef __attribute__((ext_vector_type(4))) short short4v;
typedef __attribute__((ext_vector_type(4))) float f32x4;

__device__ __forceinline__ unsigned short f2bf(float f) {
  unsigned int u = __builtin_bit_cast(unsigned int, f);
  u += 0x7fff + ((u >> 16) & 1);      // RNE
  return (unsigned short)(u >> 16);
}
__device__ __forceinline__ float bf2f(unsigned short h) {
  unsigned int u = ((unsigned int)h) << 16;
  return __builtin_bit_cast(float, u);
}

// ---- workspace layout (bf16 elements), per layer ----
// W1T [256][512]  @ 0        (W1T[n][k] = W1[k][n])
// UT  [ 64][512]  @ 131072
// W2P [64 panels] @ 163840   : panel kg (16384 elems = 32KB), j-inner layout:
//                  idx = kg*16384 + (tc*64 + j)*8 + te
//                  value = W2[t][512 + 64*kg + j], t = tc*8 + te
//                  (B-frag for (kk,g): 16B at ((4kk+g)*64 + j)*8 -> lane-contig)
// W2bT[ 512][256] @ 1212416  (W2bT[n][t] = W2[t][n])
// VT  [ 512][ 64] @ 1343488
#define L_ELEMS 1376256

struct PrepParams {
  const float* W1[3]; const float* U[3]; const float* W2[3]; const float* V[3];
  short* ws;
};

__global__ __launch_bounds__(256) void prep_weights(PrepParams p) {
  const int y = blockIdx.y;           // 0..14
  const int l = y / 5, m = y - 5 * l;
  short* wsl = p.ws + (size_t)l * L_ELEMS;
  if (m == 2) {                       // W2P j-inner panels
    const float* in = p.W2[l];
    short* out = wsl + 163840;
    const long total = 1048576;
    for (long e = (long)blockIdx.x * 256 + threadIdx.x; e < total;
         e += (long)gridDim.x * 256) {
      const int te = (int)(e & 7);
      const int j  = (int)((e >> 3) & 63);
      const int tc = (int)((e >> 9) & 31);
      const int kg = (int)(e >> 14);
      const int t  = tc * 8 + te;
      out[e] = (short)f2bf(in[(size_t)t * SC + 512 + 64 * kg + j]);
    }
    return;
  }
  const float* in; short* out; int K, istride, ioff, kshift;
  switch (m) {
    case 0: in = p.W1[l]; out = wsl;           K = 512; istride = 256;  ioff = 0; kshift = 9; break;
    case 1: in = p.U[l];  out = wsl + 131072;  K = 512; istride = 64;   ioff = 0; kshift = 9; break;
    case 3: in = p.W2[l]; out = wsl + 1212416; K = 256; istride = 4608; ioff = 0; kshift = 8; break;
    default:in = p.V[l];  out = wsl + 1343488; K = 64;  istride = 512;  ioff = 0; kshift = 6; break;
  }
  const long total = (long)K * ((m == 0) ? 256 : (m == 1) ? 64 : 512);
  for (long e = (long)blockIdx.x * 256 + threadIdx.x; e < total;
       e += (long)gridDim.x * 256) {
    const int k = (int)(e & (K - 1));
    const int n = (int)(e >> kshift);
    out[e] = (short)f2bf(in[(size_t)k * istride + ioff + n]);
  }
}

struct Params {
  const float* x;
  const float* b1[3];
  const float* b2[3];
  const float* Wout;
  const float* bout;
  const short* ws;
  float* out;
};

#define XP 520   // xs pitch in shorts
#define HP 264
#define TP 72

__global__ __launch_bounds__(NT, 1) void apg_mfma(Params p) {
  __shared__ short xs[R_T][XP];     // 33.3 KB
  __shared__ short h1s[R_T][HP];    // 16.9 KB
  __shared__ short tmps[R_T][TP];   //  4.6 KB
  __shared__ float hs[R_T][68];     //  8.7 KB  (pad 68: conflict-free)
  __shared__ float tpart[R_T][68];  //  8.7 KB  stage-C k-half partials

  const int tid  = threadIdx.x;
  const int row0 = blockIdx.x * R_T;
  const int w    = tid >> 6;         // wave 0..7
  const int l15  = tid & 15;
  const int g    = (tid & 63) >> 4;  // 0..3
  const int koff = g * 8;
  const int rh   = w >> 2;           // row-half for stages A/B/D
  const int nq   = w & 3;            // col-quarter
  const int rbase = rh * 16;

  // ---- load x tile -> bf16 LDS ----
  {
    const float4* xg = (const float4*)(p.x + (size_t)row0 * D_N);
    for (int i = tid; i < R_T * D_N / 4; i += NT) {
      float4 v = xg[i];
      const int r = i >> 7;
      const int c = (i & 127) << 2;
      short4v s4 = { (short)f2bf(v.x), (short)f2bf(v.y), (short)f2bf(v.z), (short)f2bf(v.w) };
      *(short4v*)&xs[r][c] = s4;
    }
  }
  __syncthreads();

  for (int l = 0; l < 3; ++l) {
    const short* wsl  = p.ws + (size_t)l * L_ELEMS;
    const short* W1T  = wsl;
    const short* UT   = wsl + 131072;
    const short* W2p  = wsl + 163840;
    const short* W2bT = wsl + 1212416;
    const short* VT   = wsl + 1343488;
    const float* b1 = p.b1[l];
    const float* b2 = p.b2[l];

    // ---- A-operand x fragments (rows rbase..rbase+16), for stages A+B ----
    short8 aX[16];
#pragma unroll
    for (int kk = 0; kk < 16; ++kk)
      aX[kk] = *(const short8*)&xs[rbase + l15][kk * 32 + koff];

    // ---- stage A: h1 = relu(x @ W1 + b1); wave -> 4 n-frags of its row-half ----
    for (int nf = 0; nf < 4; ++nf) {
      const int n0 = ((nq << 2) + nf) << 4;
      const short* pb = W1T + ((size_t)(n0 + l15) << 9) + koff;
      short8 bf[16];
#pragma unroll
      for (int kk = 0; kk < 16; ++kk) bf[kk] = *(const short8*)(pb + kk * 32);
      f32x4 acc = {0.f, 0.f, 0.f, 0.f};
#pragma unroll
      for (int kk = 0; kk < 16; ++kk)
        acc = __builtin_amdgcn_mfma_f32_16x16x32_bf16(aX[kk], bf[kk], acc, 0, 0, 0);
      const float bb = b1[n0 + l15];
#pragma unroll
      for (int i = 0; i < 4; ++i)
        h1s[rbase + g * 4 + i][n0 + l15] = (short)f2bf(fmaxf(acc[i] + bb, 0.f));
    }

    // ---- stage B: h = x @ U (f32); wave -> n-frag nq, its row-half ----
    {
      const int n0 = nq << 4;
      const short* pb = UT + ((size_t)(n0 + l15) << 9) + koff;
      short8 bf[16];
#pragma unroll
      for (int kk = 0; kk < 16; ++kk) bf[kk] = *(const short8*)(pb + kk * 32);
      f32x4 acc = {0.f, 0.f, 0.f, 0.f};
#pragma unroll
      for (int kk = 0; kk < 16; ++kk)
        acc = __builtin_amdgcn_mfma_f32_16x16x32_bf16(aX[kk], bf[kk], acc, 0, 0, 0);
#pragma unroll
      for (int i = 0; i < 4; ++i) hs[rbase + g * 4 + i][n0 + l15] = acc[i];
    }
    __syncthreads();   // h1s, hs ready

    // ---- stage C: tmp[r][j] = sum_k h[r,k] * (h1@W2S + b2S)[r, 64k+j] ----
    // Barrier-free: wave (nq,kh) streams its own B-frags global->reg with
    // ping-pong, covers ALL 32 rows (two aH sets), k-halves join via tpart.
    {
      const int kh  = w >> 2;
      const int kg0 = kh << 5;
      const int nl  = (nq << 4) + l15;
      short8 aH0[8], aH1[8];
#pragma unroll
      for (int kk = 0; kk < 8; ++kk) {
        aH0[kk] = *(const short8*)&h1s[l15][kk * 32 + koff];
        aH1[kk] = *(const short8*)&h1s[16 + l15][kk * 32 + koff];
      }
      float t0[4] = {0.f, 0.f, 0.f, 0.f}, t1[4] = {0.f, 0.f, 0.f, 0.f};
      // b2 einsum-bias part for this k-half
      {
        const float* pb2 = b2 + D_N + nl;
#pragma unroll 4
        for (int k = kg0; k < kg0 + 32; ++k) {
          const float b2v = pb2[k << 6];
#pragma unroll
          for (int i = 0; i < 4; ++i) {
            t0[i] += hs[g * 4 + i][k] * b2v;
            t1[i] += hs[16 + g * 4 + i][k] * b2v;
          }
        }
      }

      const short* gbase = W2p + (g << 9) + (nl << 3);
      short8 bA[8], bB[8];
      {
        const short* gp = gbase + ((size_t)kg0 << 14);
#pragma unroll
        for (int kk = 0; kk < 8; ++kk) bA[kk] = *(const short8*)(gp + (kk << 11));
      }
#pragma unroll 1
      for (int it = 0; it < 16; ++it) {
        const int kg = kg0 + it * 2;
        {
          const short* gp = gbase + ((size_t)(kg + 1) << 14);
#pragma unroll
          for (int kk = 0; kk < 8; ++kk) bB[kk] = *(const short8*)(gp + (kk << 11));
        }
        {
          f32x4 s0 = {0.f, 0.f, 0.f, 0.f}, s1 = {0.f, 0.f, 0.f, 0.f};
#pragma unroll
          for (int kk = 0; kk < 8; ++kk) {
            s0 = __builtin_amdgcn_mfma_f32_16x16x32_bf16(aH0[kk], bA[kk], s0, 0, 0, 0);
            s1 = __builtin_amdgcn_mfma_f32_16x16x32_bf16(aH1[kk], bA[kk], s1, 0, 0, 0);
          }
#pragma unroll
          for (int i = 0; i < 4; ++i) {
            t0[i] += hs[g * 4 + i][kg] * s0[i];
            t1[i] += hs[16 + g * 4 + i][kg] * s1[i];
          }
        }
        {
          const int kgn = (it == 15) ? (kg + 1) : (kg + 2);   // clamp tail
          const short* gp = gbase + ((size_t)kgn << 14);
#pragma unroll
          for (int kk = 0; kk < 8; ++kk) bA[kk] = *(const short8*)(gp + (kk << 11));
        }
        {
          f32x4 s0 = {0.f, 0.f, 0.f, 0.f}, s1 = {0.f, 0.f, 0.f, 0.f};
#pragma unroll
          for (int kk = 0; kk < 8; ++kk) {
            s0 = __builtin_amdgcn_mfma_f32_16x16x32_bf16(aH0[kk], bB[kk], s0, 0, 0, 0);
            s1 = __builtin_amdgcn_mfma_f32_16x16x32_bf16(aH1[kk], bB[kk], s1, 0, 0, 0);
          }
#pragma unroll
          for (int i = 0; i < 4; ++i) {
            t0[i] += hs[g * 4 + i][kg + 1] * s0[i];
            t1[i] += hs[16 + g * 4 + i][kg + 1] * s1[i];
          }
        }
      }

      if (kh == 0) {
#pragma unroll
        for (int i = 0; i < 4; ++i) {
          tpart[g * 4 + i][nl]      = t0[i];
          tpart[16 + g * 4 + i][nl] = t1[i];
        }
      }
      __syncthreads();
      if (kh == 1) {
#pragma unroll
        for (int i = 0; i < 4; ++i) {
          tmps[g * 4 + i][nl]      = (short)f2bf(tpart[g * 4 + i][nl] + t0[i]);
          tmps[16 + g * 4 + i][nl] = (short)f2bf(tpart[16 + g * 4 + i][nl] + t1[i]);
        }
      }
    }
    __syncthreads();

    // ---- stage D: xnew = relu(tmp@V + h1@W2b + b2[:512]) -> xs ----
    {
      short8 aT[2], aD[8];
#pragma unroll
      for (int kk = 0; kk < 2; ++kk)
        aT[kk] = *(const short8*)&tmps[rbase + l15][kk * 32 + koff];
#pragma unroll
      for (int kk = 0; kk < 8; ++kk)
        aD[kk] = *(const short8*)&h1s[rbase + l15][kk * 32 + koff];
      for (int ti = 0; ti < 8; ++ti) {
        const int n0 = ((ti << 2) + nq) << 4;
        const short* pv = VT + ((size_t)(n0 + l15) << 6) + koff;
        const short* pw = W2bT + ((size_t)(n0 + l15) << 8) + koff;
        short8 bv[2], bw[8];
#pragma unroll
        for (int kk = 0; kk < 2; ++kk) bv[kk] = *(const short8*)(pv + kk * 32);
#pragma unroll
        for (int kk = 0; kk < 8; ++kk) bw[kk] = *(const short8*)(pw + kk * 32);
        f32x4 acc = {0.f, 0.f, 0.f, 0.f};
#pragma unroll
        for (int kk = 0; kk < 2; ++kk)
          acc = __builtin_amdgcn_mfma_f32_16x16x32_bf16(aT[kk], bv[kk], acc, 0, 0, 0);
#pragma unroll
        for (int kk = 0; kk < 8; ++kk)
          acc = __builtin_amdgcn_mfma_f32_16x16x32_bf16(aD[kk], bw[kk], acc, 0, 0, 0);
        const float bb = b2[n0 + l15];
#pragma unroll
        for (int i = 0; i < 4; ++i)
          xs[rbase + g * 4 + i][n0 + l15] = (short)f2bf(fmaxf(acc[i] + bb, 0.f));
      }
    }
    __syncthreads();
  }

  // ---- out = x @ Wout + bout ----
  {
    const int r  = tid >> 4;
    const int cl = tid & 15;
    float acc = 0.f;
    for (int c = cl; c < D_N; c += 16)
      acc = fmaf(bf2f((unsigned short)xs[r][c]), p.Wout[c], acc);
#pragma unroll
    for (int s = 1; s < 16; s <<= 1) acc += __shfl_xor(acc, s, 64);
    if (cl == 0) p.out[row0 + r] = acc + p.bout[0];
  }
}

extern "C" void kernel_launch(void* const* d_in, const int* in_sizes, int n_in,
                              void* d_out, int out_size, void* d_ws, size_t ws_size,
                              hipStream_t stream) {
  (void)in_sizes; (void)n_in; (void)ws_size; (void)out_size;
  PrepParams pp;
  Params p;
  p.x = (const float*)d_in[0];
  for (int l = 0; l < 3; ++l) {
    const int base = 1 + l * 6;
    pp.U[l]  = (const float*)d_in[base + 0];
    pp.V[l]  = (const float*)d_in[base + 1];
    pp.W1[l] = (const float*)d_in[base + 2];
    p.b1[l]  = (const float*)d_in[base + 3];
    pp.W2[l] = (const float*)d_in[base + 4];
    p.b2[l]  = (const float*)d_in[base + 5];
  }
  p.Wout = (const float*)d_in[19];
  p.bout = (const float*)d_in[20];
  p.ws   = (const short*)d_ws;
  p.out  = (float*)d_out;
  pp.ws  = (short*)d_ws;

  hipLaunchKernelGGL(prep_weights, dim3(1024, 15), dim3(256), 0, stream, pp);
  hipLaunchKernelGGL(apg_mfma, dim3(B_N / R_T), dim3(NT), 0, stream, p);
}